// Round 6
// baseline (155.330 us; speedup 1.0000x reference)
//
#include <hip/hip_runtime.h>
#include <hip/hip_bf16.h>

typedef __attribute__((ext_vector_type(8))) short bf16x8;   // 8 bf16 = 4 VGPR (MFMA A/B frag)
typedef __attribute__((ext_vector_type(4))) float f32x4;    // MFMA C/D frag

#define DEVI __device__ __forceinline__

constexpr int SEQ_   = 2048;
constexpr int HEADS  = 16;
constexpr int DHEAD  = 64;
constexpr int DMODEL = 1024;

DEVI unsigned short f2bf(float x) {
  __hip_bfloat16 h = __float2bfloat16(x);   // RNE
  return __builtin_bit_cast(unsigned short, h);
}

DEVI f32x4 MFMA(bf16x8 a, bf16x8 b, f32x4 c) {
  return __builtin_amdgcn_mfma_f32_16x16x32_bf16(a, b, c, 0, 0, 0);
}

// ---------------------------------------------------------------- convert ---
__global__ void conv3_kernel(const float* s0, const float* s1, const float* s2,
                             unsigned short* d0, unsigned short* d1, unsigned short* d2,
                             int n) {
  const float* s = (blockIdx.y == 0) ? s0 : (blockIdx.y == 1) ? s1 : s2;
  unsigned short* d = (blockIdx.y == 0) ? d0 : (blockIdx.y == 1) ? d1 : d2;
  int i = (blockIdx.x * 256 + threadIdx.x) * 8;
  if (i >= n) return;
  const float4* p = (const float4*)(s + i);
  float4 v0 = p[0], v1 = p[1];
  union { unsigned short u[8]; bf16x8 v; } t;
  t.u[0] = f2bf(v0.x); t.u[1] = f2bf(v0.y); t.u[2] = f2bf(v0.z); t.u[3] = f2bf(v0.w);
  t.u[4] = f2bf(v1.x); t.u[5] = f2bf(v1.y); t.u[6] = f2bf(v1.z); t.u[7] = f2bf(v1.w);
  *(bf16x8*)(d + i) = t.v;
}

// ------------------------------------------------------------- projection ---
// One fused launch for Q/K/V (blockIdx.z selects).
// z==0 (Q): out (b,h,s,d) row-major.
// z==1 (K): 4KB tiles in MFMA-FRAGMENT ORDER: tile (bh, s>>5), frag
//           f = (d>>5)*2 + ((s>>4)&1), lane = ((d&31)>>3)*16 + (s&15), elem d&7.
// z==2 (V): 4KB tiles frag-order: frag dc = d>>4, lane = ((s&31)>>3)*16 + (d&15),
//           elem s&7.
// Fragment order makes attn LDS reads lane-linear (zero bank conflicts) while
// keeping global_load_lds staging fully linear.
__global__ __launch_bounds__(256) void proj3_kernel(
    const unsigned short* __restrict__ X0, const unsigned short* __restrict__ X1,
    const unsigned short* __restrict__ X2,
    const unsigned short* __restrict__ W0, const unsigned short* __restrict__ W1,
    const unsigned short* __restrict__ W2,
    const float* __restrict__ bi0, const float* __restrict__ bi1,
    const float* __restrict__ bi2,
    unsigned short* __restrict__ o0, unsigned short* __restrict__ o1,
    unsigned short* __restrict__ o2) {
  const int z = blockIdx.z;
  const unsigned short* X = (z == 0) ? X0 : (z == 1) ? X1 : X2;
  const unsigned short* W = (z == 0) ? W0 : (z == 1) ? W1 : W2;
  const float* bias        = (z == 0) ? bi0 : (z == 1) ? bi1 : bi2;
  unsigned short* out      = (z == 0) ? o0 : (z == 1) ? o1 : o2;

  __shared__ unsigned short Abuf[2][128 * 32];
  __shared__ unsigned short Bbuf[2][128 * 32];
  const int tid  = threadIdx.x;
  const int lane = tid & 63, wv = tid >> 6;
  const int q = lane >> 4, r = lane & 15;
  const int wrow = wv >> 1, wcol = wv & 1;
  const int rowA0 = blockIdx.x * 128, colB0 = blockIdx.y * 128;

  const char* Ag = (const char*)(X + (size_t)rowA0 * DMODEL);
  const char* Bg = (const char*)(W + (size_t)colB0 * DMODEL);

  f32x4 acc[4][4] = {};

  auto stage = [&](int ks, int buf) {
    const int koff = ks * 64;
#pragma unroll
    for (int i = 0; i < 2; ++i) {
      const int b   = (i * 256 + tid) * 16;
      const int row = b >> 6, col = b & 63;
      __builtin_amdgcn_global_load_lds(
          (const __attribute__((address_space(1))) void*)(Ag + (size_t)row * (DMODEL * 2) + koff + col),
          (__attribute__((address_space(3))) void*)((char*)&Abuf[buf][0] + i * 4096 + wv * 1024),
          16, 0, 0);
      __builtin_amdgcn_global_load_lds(
          (const __attribute__((address_space(1))) void*)(Bg + (size_t)row * (DMODEL * 2) + koff + col),
          (__attribute__((address_space(3))) void*)((char*)&Bbuf[buf][0] + i * 4096 + wv * 1024),
          16, 0, 0);
    }
  };

  stage(0, 0);
  for (int ks = 0; ks < 32; ++ks) {
    __syncthreads();
    if (ks + 1 < 32) stage(ks + 1, (ks + 1) & 1);
    const unsigned short* A  = &Abuf[ks & 1][0];
    const unsigned short* Bt = &Bbuf[ks & 1][0];
    bf16x8 af[4], bfr[4];
#pragma unroll
    for (int t = 0; t < 4; ++t) {
      af[t]  = *(const bf16x8*)(A  + (wrow * 64 + t * 16 + r) * 32 + q * 8);
      bfr[t] = *(const bf16x8*)(Bt + (wcol * 64 + t * 16 + r) * 32 + q * 8);
    }
#pragma unroll
    for (int m = 0; m < 4; ++m)
#pragma unroll
      for (int n = 0; n < 4; ++n)
        acc[m][n] = MFMA(af[m], bfr[n], acc[m][n]);
  }

#pragma unroll
  for (int m = 0; m < 4; ++m) {
#pragma unroll
    for (int n = 0; n < 4; ++n) {
      const int e  = colB0 + wcol * 64 + n * 16 + r;
      const float bv = bias[e];
      const int h = e >> 6, dd = e & 63;
      const int nrow0 = rowA0 + wrow * 64 + m * 16 + q * 4;
      const int bb = nrow0 >> 11, ss0 = nrow0 & 2047;
      const size_t bh = (size_t)(bb * HEADS + h);
      if (z == 0) {
#pragma unroll
        for (int j = 0; j < 4; ++j)
          out[(bh * SEQ_ + (ss0 + j)) * DHEAD + dd] = f2bf(acc[m][n][j] + bv);
      } else if (z == 1) {
#pragma unroll
        for (int j = 0; j < 4; ++j) {
          const int s = ss0 + j;
          const size_t off = (bh * 64 + (size_t)(s >> 5)) * 2048
                           + (size_t)(((dd >> 5) * 2 + ((s >> 4) & 1)) * 512)
                           + (size_t)(((((dd & 31) >> 3) << 4) + (s & 15)) * 8)
                           + (dd & 7);
          out[off] = f2bf(acc[m][n][j] + bv);
        }
      } else {
        union { unsigned short u[4]; uint2 v; } pk;
#pragma unroll
        for (int j = 0; j < 4; ++j) pk.u[j] = f2bf(acc[m][n][j] + bv);
        const size_t off = (bh * 64 + (size_t)(ss0 >> 5)) * 2048
                         + (size_t)((dd >> 4) * 512)
                         + (size_t)(((((ss0 & 31) >> 3) << 4) + (dd & 15)) * 8)
                         + (ss0 & 7);
        *(uint2*)&out[off] = pk.v;   // 4 consecutive s stay in one octet
      }
    }
  }
}

// -------------------------------------------------------------- attention ---
// 2048 blocks x 128 thr (2 waves) = 8 blocks/CU, ALL resident (LDS 18.9KB).
// Balanced split-K over strip pairs: for pair p (long tile L=63-p, short tile p):
//   block (p, ab=0): L iters [0,32)            -> partial (oacc, sum p) slot 0
//   block (p, ab=1): L iters [32,64-p) partial -> slot 1; then ALL of tile p,
//                    written final to d_out.
// Fixed-max softmax makes partial merge a pure sum; reduce_kernel normalizes.
// K/V staged via global_load_lds from fragment-order global tiles -> linear
// staging, lane-linear ds_read_b128 (zero conflicts).
__global__ __launch_bounds__(128, 4) void attn_kernel(const unsigned short* __restrict__ qb,
                                                      const unsigned short* __restrict__ kt,
                                                      const unsigned short* __restrict__ vt,
                                                      const unsigned short* __restrict__ Er,
                                                      float* __restrict__ out,
                                                      float* __restrict__ pO,
                                                      float* __restrict__ pL) {
  __shared__ unsigned short k_lds[2][2048];     // frag-order 4KB tile per buf
  __shared__ unsigned short v_lds[2][2048];
  __shared__ unsigned short p_lds[2][16][40];   // per-wave P bounce, 80B stride

  const int tid  = threadIdx.x;
  const int lane = tid & 63, wv = tid >> 6;
  const int q = lane >> 4, r = lane & 15;

  const int lid = blockIdx.x;
  const int xcd = lid & 7, idx = lid >> 3;      // 256 per XCD
  const int bh  = (xcd << 2) | (idx & 3);       // 4 bh pinned per XCD L2
  const int rest = idx >> 2;                    // 0..63
  const int p = rest >> 1, ab = rest & 1;
  const int Lt = 63 - p;
  const int sid = (bh << 5) | p;                // strip-pair id 0..1023
  const int bb = bh >> 4, hh = bh & 15;

  const unsigned short* qbh = qb + (size_t)bh * SEQ_ * DHEAD;
  const char* ktb = (const char*)(kt + (size_t)bh * 64 * 2048);
  const char* vtb = (const char*)(vt + (size_t)bh * 64 * 2048);

  const f32x4 zero4 = {0.f, 0.f, 0.f, 0.f};

  auto stage = [&](int ktile, int buf) {
#pragma unroll
    for (int c = 0; c < 2; ++c) {
      __builtin_amdgcn_global_load_lds(
          (const __attribute__((address_space(1))) void*)(ktb + (size_t)ktile * 4096 + (c * 128 + tid) * 16),
          (__attribute__((address_space(3))) void*)((char*)&k_lds[buf][0] + c * 2048 + wv * 1024),
          16, 0, 0);
      __builtin_amdgcn_global_load_lds(
          (const __attribute__((address_space(1))) void*)(vtb + (size_t)ktile * 4096 + (c * 128 + tid) * 16),
          (__attribute__((address_space(3))) void*)((char*)&v_lds[buf][0] + c * 2048 + wv * 1024),
          16, 0, 0);
    }
  };

  // po == nullptr -> final mode (normalize + store to d_out)
  auto run_strip = [&](int tile, int it0, int itN, float* po, float* pl) {
    const int s0 = tile * 32 + wv * 16;
    __syncthreads();                            // prev strip done reading bufs
    stage(it0, 0);

    bf16x8 qf0 = *(const bf16x8*)(qbh + (size_t)(s0 + r) * DHEAD + q * 8);
    bf16x8 qf1 = *(const bf16x8*)(qbh + (size_t)(s0 + r) * DHEAD + 32 + q * 8);

    f32x4 oacc[4] = {};
    float lpart[4] = {0.f, 0.f, 0.f, 0.f};
    f32x4 qer0;
    {
      const int l0 = 2032 + it0 * 32 - s0 + r;  // in [0, 2047] for all call sites
      bf16x8 e00 = *(const bf16x8*)(Er + (size_t)l0 * DHEAD + q * 8);
      bf16x8 e01 = *(const bf16x8*)(Er + (size_t)l0 * DHEAD + 32 + q * 8);
      qer0 = MFMA(qf1, e01, MFMA(qf0, e00, zero4));
    }

#pragma unroll 1
    for (int it = it0; it < itN; ++it) {
      const int cur = (it - it0) & 1;
      const int t0 = it * 32;
      const int lbase = 2032 + t0 - s0;

      __syncthreads();                          // buf[cur] staged & waves synced

      int l1 = lbase + 16 + r; l1 = l1 < 2047 ? l1 : 2047;
      int l2 = lbase + 32 + r; l2 = l2 < 2047 ? l2 : 2047;
      bf16x8 e10 = *(const bf16x8*)(Er + (size_t)l1 * DHEAD + q * 8);
      bf16x8 e11 = *(const bf16x8*)(Er + (size_t)l1 * DHEAD + 32 + q * 8);
      bf16x8 e20 = *(const bf16x8*)(Er + (size_t)l2 * DHEAD + q * 8);
      bf16x8 e21 = *(const bf16x8*)(Er + (size_t)l2 * DHEAD + 32 + q * 8);

      if (it + 1 < itN) stage(it + 1, 1 - cur); // fire-and-forget

      // fragment-order LDS reads: lane-linear, conflict-free
      const unsigned short* KL = &k_lds[cur][0];
      const unsigned short* VL = &v_lds[cur][0];
      bf16x8 kf00 = *(const bf16x8*)(KL + lane * 8);          // (ct0,kc0)
      bf16x8 kf10 = *(const bf16x8*)(KL + 512 + lane * 8);    // (ct1,kc0)
      bf16x8 kf01 = *(const bf16x8*)(KL + 1024 + lane * 8);   // (ct0,kc1)
      bf16x8 kf11 = *(const bf16x8*)(KL + 1536 + lane * 8);   // (ct1,kc1)

      __builtin_amdgcn_s_setprio(1);
      f32x4 s40  = MFMA(qf1, kf01, MFMA(qf0, kf00, zero4));
      f32x4 s41  = MFMA(qf1, kf11, MFMA(qf0, kf10, zero4));
      f32x4 qer1 = MFMA(qf1, e11, MFMA(qf0, e10, zero4));
      f32x4 qer2 = MFMA(qf1, e21, MFMA(qf0, e20, zero4));
      __builtin_amdgcn_s_setprio(0);

      // fixed-max softmax: rows sl = q*4+j, cols spread over 16-lane r-group
#pragma unroll
      for (int j = 0; j < 4; ++j) {
        const int sl = q * 4 + j;
        const int idxw = r + 15 - sl;           // window col for ct=0 (0..30)
        const int srcl = (q << 4) | (idxw & 15);
        const float g0 = __shfl(qer0[j], srcl);
        const float g1 = __shfl(qer1[j], srcl);
        const float g2 = __shfl(qer2[j], srcl);
        const bool lo = (idxw < 16);
        float sv0 = (s40[j] + (lo ? g0 : g1)) * 0.125f;
        float sv1 = (s41[j] + (lo ? g1 : g2)) * 0.125f;
        if (t0 + r      > s0 + sl) sv0 = -1e30f;   // causal
        if (t0 + 16 + r > s0 + sl) sv1 = -1e30f;
        const float p0 = __expf(sv0);
        const float p1 = __expf(sv1);
        lpart[j] += p0 + p1;
        p_lds[wv][sl][r]      = f2bf(p0);
        p_lds[wv][sl][16 + r] = f2bf(p1);
      }

      // PV: A = P (LDS bounce), B = V frag-order (lane-linear)
      bf16x8 pf  = *(const bf16x8*)(&p_lds[wv][r][0] + q * 8);
      bf16x8 vf0 = *(const bf16x8*)(VL + lane * 8);
      bf16x8 vf1 = *(const bf16x8*)(VL + 512 + lane * 8);
      bf16x8 vf2 = *(const bf16x8*)(VL + 1024 + lane * 8);
      bf16x8 vf3 = *(const bf16x8*)(VL + 1536 + lane * 8);
      __builtin_amdgcn_s_setprio(1);
      oacc[0] = MFMA(pf, vf0, oacc[0]);
      oacc[1] = MFMA(pf, vf1, oacc[1]);
      oacc[2] = MFMA(pf, vf2, oacc[2]);
      oacc[3] = MFMA(pf, vf3, oacc[3]);
      __builtin_amdgcn_s_setprio(0);
      qer0 = qer2;                              // slide window
    }

    // epilogue
#pragma unroll
    for (int j = 0; j < 4; ++j) {
      float ls = lpart[j];
#pragma unroll
      for (int d = 1; d < 16; d <<= 1) ls += __shfl_xor(ls, d);
      const int row = wv * 16 + q * 4 + j;
      if (po) {                                 // partial: unnormalized sums
#pragma unroll
        for (int dc = 0; dc < 4; ++dc)
          po[(size_t)row * 64 + dc * 16 + r] = oacc[dc][j];
        if (r == 0) pl[row] = ls;
      } else {                                  // final: normalize + store
        const float inv = 1.0f / ls;
        const int ss = tile * 32 + row;
#pragma unroll
        for (int dc = 0; dc < 4; ++dc) {
          const int dd = dc * 16 + r;
          out[((size_t)(bb * SEQ_ + ss)) * DMODEL + hh * DHEAD + dd] = oacc[dc][j] * inv;
        }
      }
    }
  };

  if (ab == 0) {
    run_strip(Lt, 0, 32, pO + (size_t)(sid * 2) * 2048, pL + (size_t)(sid * 2) * 32);
  } else {
    run_strip(Lt, 32, 64 - p, pO + (size_t)(sid * 2 + 1) * 2048, pL + (size_t)(sid * 2 + 1) * 32);
    run_strip(p, 0, p + 1, nullptr, nullptr);
  }
}

// ---------------------------------------------------------------- reduce ----
// Merge the two partials of each long strip: O = (oA+oB)/(lA+lB).
__global__ __launch_bounds__(256) void reduce_kernel(const float* __restrict__ pO,
                                                     const float* __restrict__ pL,
                                                     float* __restrict__ out) {
  const int sid = blockIdx.x;                   // bh*32 + p
  const int bh = sid >> 5, p = sid & 31;
  const int bb = bh >> 4, hh = bh & 15;
  const int srow = (63 - p) * 32;
  const int tid = threadIdx.x;
  const int row = tid >> 3, dseg = (tid & 7) * 8;

  const float* a = pO + (size_t)(sid * 2) * 2048 + row * 64 + dseg;
  const float* b = a + 2048;
  const float la = pL[(size_t)(sid * 2) * 32 + row];
  const float lb = pL[(size_t)(sid * 2 + 1) * 32 + row];
  const float inv = 1.0f / (la + lb);

  float4 x0 = ((const float4*)a)[0], x1 = ((const float4*)a)[1];
  float4 y0 = ((const float4*)b)[0], y1 = ((const float4*)b)[1];
  float4 o0, o1;
  o0.x = (x0.x + y0.x) * inv; o0.y = (x0.y + y0.y) * inv;
  o0.z = (x0.z + y0.z) * inv; o0.w = (x0.w + y0.w) * inv;
  o1.x = (x1.x + y1.x) * inv; o1.y = (x1.y + y1.y) * inv;
  o1.z = (x1.z + y1.z) * inv; o1.w = (x1.w + y1.w) * inv;

  float* dst = out + ((size_t)(bb * SEQ_) + srow + row) * DMODEL + hh * DHEAD + dseg;
  ((float4*)dst)[0] = o0;
  ((float4*)dst)[1] = o1;
}

// ------------------------------------------------------------------ launch ---
extern "C" void kernel_launch(void* const* d_in, const int* in_sizes, int n_in,
                              void* d_out, int out_size, void* d_ws, size_t ws_size,
                              hipStream_t stream) {
  const float* query = (const float*)d_in[0];
  const float* key   = (const float*)d_in[1];
  const float* value = (const float*)d_in[2];
  const float* Wq    = (const float*)d_in[3];
  const float* bq    = (const float*)d_in[4];
  const float* Wk    = (const float*)d_in[5];
  const float* bk    = (const float*)d_in[6];
  const float* Wv    = (const float*)d_in[7];
  const float* bv    = (const float*)d_in[8];
  const float* Er    = (const float*)d_in[9];

  char* ws = (char*)d_ws;
  unsigned short* qb   = (unsigned short*)(ws + (0u  << 20));  // (B,H,S,64) bf16  8MB
  unsigned short* ktil = (unsigned short*)(ws + (8u  << 20));  // K frag-tiles     8MB
  unsigned short* vtil = (unsigned short*)(ws + (16u << 20));  // V frag-tiles     8MB
  float*          pO   = (float*)(ws + (24u << 20));           // partial O       16MB (reuses 32MB+ Xq head)
  float*          pL   = (float*)(ws + (40u << 20));           // partial l      256KB (dead Xk head)
  unsigned short* Xq   = (unsigned short*)(ws + (32u << 20));  // (B*S, D) bf16    8MB (dead after proj3)
  unsigned short* Xk   = (unsigned short*)(ws + (40u << 20));
  unsigned short* Xv   = (unsigned short*)(ws + (48u << 20));
  unsigned short* Wqb  = (unsigned short*)(ws + (56u << 20));  // (D, D) bf16      2MB
  unsigned short* Wkb  = (unsigned short*)(ws + (58u << 20));
  unsigned short* Wvb  = (unsigned short*)(ws + (60u << 20));
  unsigned short* Erb  = (unsigned short*)(ws + (62u << 20));  // (2048, 64)     256KB

  conv3_kernel<<<dim3(2048, 3), 256, 0, stream>>>(query, key, value, Xq, Xk, Xv,
                                                  2 * SEQ_ * DMODEL);
  conv3_kernel<<<dim3(512, 3), 256, 0, stream>>>(Wq, Wk, Wv, Wqb, Wkb, Wvb,
                                                 DMODEL * DMODEL);
  conv3_kernel<<<dim3(64, 1), 256, 0, stream>>>(Er, Er, Er, Erb, Erb, Erb,
                                                SEQ_ * DHEAD);

  proj3_kernel<<<dim3(32, 8, 3), 256, 0, stream>>>(Xq, Xk, Xv, Wqb, Wkb, Wvb,
                                                   bq, bk, bv, qb, ktil, vtil);

  attn_kernel<<<dim3(2048), 128, 0, stream>>>(qb, ktil, vtil, Erb,
                                              (float*)d_out, pO, pL);

  reduce_kernel<<<dim3(1024), 256, 0, stream>>>(pO, pL, (float*)d_out);
}